// Round 13
// baseline (286.795 us; speedup 1.0000x reference)
//
#include <hip/hip_runtime.h>
#include <hip/hip_bf16.h>

typedef __hip_bfloat16 bf16;
typedef short v8s __attribute__((ext_vector_type(8)));   // 8 bf16 (4 VGPRs), MFMA A/B frag
typedef float v4f __attribute__((ext_vector_type(4)));   // MFMA C/D frag
typedef float v2f __attribute__((ext_vector_type(2)));   // cvt_pk_f32_fp8 result

constexpr int NN    = 50000;   // nodes
constexpr int NE    = 800000;  // raw edges (self-loops handled analytically)
constexpr int CIN   = 256;
constexpr int HC    = 256;     // H*C
constexpr int NH    = 4;
constexpr int NOUT  = 40;
constexpr int NPAD  = 48;      // W2T padded cols (3 x 16)
constexpr int SCB   = 196;     // scan blocks (196*256 >= NN)
constexpr int B1    = 128;     // edge-pass blocks
constexpr int CH    = (NE + B1 - 1) / B1;   // 6250 edges/chunk
constexpr int NB    = (NN + 255) >> 8;      // 196 dst-buckets (d>>8)

// ---------------- workspace layout ----------------
constexpr size_t al256(size_t x){ return (x + 255) & ~(size_t)255; }
constexpr size_t WS_FLAGS = 0;                                   // 2 ints
constexpr size_t WS_EW1   = 256;                                 // NE float4 (unused; layout kept)
constexpr size_t WS_W1T   = al256(WS_EW1   + (size_t)NE*16);     // [n][k] 256x256 bf16
constexpr size_t WS_AS1N  = al256(WS_W1T   + (size_t)CIN*HC*2);
constexpr size_t WS_AD1N  = al256(WS_AS1N  + HC*2);
constexpr size_t WS_B1N   = al256(WS_AD1N  + HC*2);
constexpr size_t WS_W2T   = al256(WS_B1N   + HC*2);              // [n][k] 48x256 bf16 (zero-padded)
constexpr size_t WS_AS2N  = al256(WS_W2T   + (size_t)NPAD*HC*2);
constexpr size_t WS_AD2N  = al256(WS_AS2N  + NOUT*2);
constexpr size_t WS_B2N   = al256(WS_AD2N  + NOUT*2);
constexpr size_t WS_COUNTS= al256(WS_B2N   + NOUT*2);
constexpr size_t WS_CURSOR= al256(WS_COUNTS+ (size_t)NN*4);
constexpr size_t WS_ROWPTR= al256(WS_CURSOR+ (size_t)NN*4);
constexpr size_t WS_EIDX  = al256(WS_ROWPTR+ (size_t)(NN+1)*4);  // NE int (src per CSR slot)
constexpr size_t WS_H1    = al256(WS_EIDX  + (size_t)NE*4);      // NN*HC fp8 (1B)
constexpr size_t WS_ALS1  = al256(WS_H1    + (size_t)NN*HC);
constexpr size_t WS_ALD1  = al256(WS_ALS1  + (size_t)NN*NH*4);
constexpr size_t WS_Y1    = al256(WS_ALD1  + (size_t)NN*NH*4);   // NN*HC bf16
constexpr size_t WS_H2    = al256(WS_Y1    + (size_t)NN*HC*2);   // NN*64 fp8 (64B row = 1 line)
constexpr size_t WS_ALS2  = al256(WS_H2    + (size_t)NN*64);
constexpr size_t WS_ALD2  = al256(WS_ALS2  + (size_t)NN*4);
constexpr size_t WS_EW2   = al256(WS_ALD2  + (size_t)NN*4);      // NE float (unused; layout kept)
constexpr size_t WS_BSUM  = al256(WS_EW2   + (size_t)NE*4);      // 256 int
constexpr size_t WS_BOFF  = al256(WS_BSUM  + 1024);              // 256 int
constexpr size_t WS_GCNT  = al256(WS_BOFF  + 1024);              // 256*B1 int
constexpr size_t WS_ROFF  = al256(WS_GCNT  + (size_t)256*B1*4);  // 256*B1 int
constexpr size_t WS_BBASE = al256(WS_ROFF  + (size_t)256*B1*4);  // 257 int
constexpr size_t WS_EBUF  = al256(WS_BBASE + 1056);              // NE int2

// ---------------- convert virtual index space (weights only) ----------------
constexpr int CV_W1  = 0;
constexpr int CV_AS1 = CV_W1  + CIN*HC;
constexpr int CV_AD1 = CV_AS1 + HC;
constexpr int CV_B1  = CV_AD1 + HC;
constexpr int CV_W2  = CV_B1  + HC;
constexpr int CV_AS2 = CV_W2  + HC*NOUT;
constexpr int CV_AD2 = CV_AS2 + NOUT;
constexpr int CV_B2  = CV_AD2 + NOUT;
constexpr int CV_END = CV_B2  + NOUT;

__device__ __forceinline__ float b2f(bf16 v) { return __bfloat162float(v); }
__device__ __forceinline__ bf16  f2b(float v){ return __float2bfloat16(v); }
__device__ __forceinline__ float bits2f(unsigned short u){ return __uint_as_float(((unsigned)u) << 16); }
__device__ __forceinline__ unsigned short f2bits(float v){
  bf16 t = __float2bfloat16(v);
  return *reinterpret_cast<unsigned short*>(&t);
}
__device__ __forceinline__ float lrelu(float x){ return x > 0.f ? x : 0.2f * x; }

__device__ __forceinline__ float wave_sum(float v){
  #pragma unroll
  for (int off = 32; off; off >>= 1) v += __shfl_xor(v, off, 64);
  return v;
}
__device__ __forceinline__ float wave_max(float v){
  #pragma unroll
  for (int off = 32; off; off >>= 1) v = fmaxf(v, __shfl_xor(v, off, 64));
  return v;
}

// ---------------- init: zero counts/cursor/w2t-pad + dtype detection ----------
constexpr int INIT_B = (2*NN + 2048 + 255) / 256;   // zero-fill blocks
__global__ __launch_bounds__(256) void k_init(const unsigned short* __restrict__ xu,
                                              const unsigned* __restrict__ eu,
                                              char* __restrict__ ws){
  int b = blockIdx.x;
  if (b == INIT_B){                       // detect block (wave 0 only)
    int lane = threadIdx.x;
    if (lane < 64){
      int* flags = (int*)(ws + WS_FLAGS);
      int cnt = 0;
      for (int i = lane; i < 256; i += 64){
        int e = (xu[i] >> 7) & 0xFF;
        cnt += (e >= 0x60 && e <= 0x8F) ? 1 : 0;
      }
      #pragma unroll
      for (int off = 32; off; off >>= 1) cnt += __shfl_xor(cnt, off, 64);
      unsigned odd = eu[2 * lane + 1];
      #pragma unroll
      for (int off = 32; off; off >>= 1) odd |= __shfl_xor(odd, off, 64);
      if (lane == 0){
        flags[0] = (cnt < 218) ? 1 : 0;   // 1 = floats are f32
        flags[1] = (odd == 0)  ? 1 : 0;   // 1 = edges are int64
      }
    }
    return;
  }
  int g = b * 256 + threadIdx.x;
  int* counts = (int*)(ws + WS_COUNTS);
  int* cursor = (int*)(ws + WS_CURSOR);
  bf16* w2t   = (bf16*)(ws + WS_W2T);
  if (g < NN) counts[g] = 0;
  else if (g < 2*NN) cursor[g - NN] = 0;
  else if (g < 2*NN + 2048){
    int i = g - 2*NN;                     // zero pad rows 40..47 of w2t
    w2t[(NOUT + (i >> 8)) * CIN + (i & 255)] = f2b(0.f);
  }
}

__device__ __forceinline__ bf16 cvt_b(const void* src, int i, int f32m){
  if (f32m) return __float2bfloat16(((const float*)src)[i]);
  return ((const bf16*)src)[i];
}

// convert weights + FUSED edge histogram (counts + per-chunk gcnt, one read).
__global__ __launch_bounds__(256) void k_convert(
    const void* __restrict__ W1,
    const void* __restrict__ as1,const void* __restrict__ ad1,
    const void* __restrict__ b1, const void* __restrict__ W2,
    const void* __restrict__ as2,const void* __restrict__ ad2,
    const void* __restrict__ b2, const void* __restrict__ ei,
    char* __restrict__ ws){
  const int* flags = (const int*)(ws + WS_FLAGS);
  int f32m = flags[0], i64m = flags[1];
  int blk = blockIdx.x, tid = threadIdx.x;
  if (blk < B1){
    __shared__ int h[256];
    int* counts = (int*)(ws + WS_COUNTS);
    int* gcnt   = (int*)(ws + WS_GCNT);
    h[tid] = 0;
    __syncthreads();
    int i0 = blk * CH, i1 = min(i0 + CH, NE);
    for (int i = i0 + tid; i < i1; i += 256){
      int d = i64m ? (int)((const long long*)ei)[(size_t)NE + i] : ((const int*)ei)[NE + i];
      atomicAdd(&counts[d], 1);
      atomicAdd(&h[d >> 8], 1);
    }
    __syncthreads();
    gcnt[tid * B1 + blk] = h[tid];        // layout [bucket][block]
    return;
  }
  bf16* w1t  = (bf16*)(ws + WS_W1T);
  bf16* as1n = (bf16*)(ws + WS_AS1N);
  bf16* ad1n = (bf16*)(ws + WS_AD1N);
  bf16* b1n  = (bf16*)(ws + WS_B1N);
  bf16* w2t  = (bf16*)(ws + WS_W2T);
  bf16* as2n = (bf16*)(ws + WS_AS2N);
  bf16* ad2n = (bf16*)(ws + WS_AD2N);
  bf16* b2n  = (bf16*)(ws + WS_B2N);
  for (int g = (blk - B1) * 256 + tid; g < CV_END; g += (gridDim.x - B1) * 256){
    if      (g < CV_AS1){ int i = g-CV_W1; int k = i >> 8, n = i & 255;
      w1t[n*CIN + k] = cvt_b(W1, i, f32m); }                       // transpose
    else if (g < CV_AD1) as1n[g-CV_AS1] = cvt_b(as1,g-CV_AS1, f32m);
    else if (g < CV_B1 ) ad1n[g-CV_AD1] = cvt_b(ad1,g-CV_AD1, f32m);
    else if (g < CV_W2 ) b1n [g-CV_B1 ] = cvt_b(b1, g-CV_B1,  f32m);
    else if (g < CV_AS2){ int i = g-CV_W2; int k = i / NOUT, n = i - k*NOUT;
      w2t[n*CIN + k] = cvt_b(W2, i, f32m); }                       // transpose (rows 40..47 pre-zeroed)
    else if (g < CV_AD2) as2n[g-CV_AS2] = cvt_b(as2,g-CV_AS2, f32m);
    else if (g < CV_B2 ) ad2n[g-CV_AD2] = cvt_b(ad2,g-CV_AD2, f32m);
    else                 b2n [g-CV_B2 ] = cvt_b(b2, g-CV_B2,  f32m);
  }
}

// ---------------- parallel CSR scan (real edges only; self-loops analytic) -----
__global__ __launch_bounds__(256) void k_scan_part(const int* __restrict__ counts, int* __restrict__ bsum){
  __shared__ int lds[256];
  int t = threadIdx.x;
  int idx = blockIdx.x * 256 + t;
  int v = (idx < NN) ? counts[idx] : 0;
  lds[t] = v;
  #pragma unroll
  for (int s = 128; s > 0; s >>= 1){
    __syncthreads();
    if (t < s) lds[t] += lds[t + s];
  }
  if (t == 0) bsum[blockIdx.x] = lds[0];
}

// scan_mid (block 0) + gscan (block 1) fused: both are single-block scans.
__global__ __launch_bounds__(256) void k_scan_mid2(const int* __restrict__ bsum, int* __restrict__ boff,
                                                   int* __restrict__ row_ptr,
                                                   const int* __restrict__ gcnt, int* __restrict__ roff,
                                                   int* __restrict__ bbase){
  __shared__ int lds[256];
  int t = threadIdx.x;
  if (blockIdx.x == 0){
    int v = (t < SCB) ? bsum[t] : 0;
    lds[t] = v;
    for (int off = 1; off < 256; off <<= 1){
      __syncthreads();
      int u = (t >= off) ? lds[t - off] : 0;
      __syncthreads();
      lds[t] += u;
    }
    __syncthreads();
    if (t < SCB) boff[t] = lds[t] - v;   // exclusive
    if (t == 0) row_ptr[NN] = NE;
  } else {
    int tot = 0;
    for (int blk = 0; blk < B1; ++blk) tot += gcnt[t * B1 + blk];
    lds[t] = tot;
    for (int off = 1; off < 256; off <<= 1){
      __syncthreads();
      int u = (t >= off) ? lds[t - off] : 0;
      __syncthreads();
      lds[t] += u;
    }
    __syncthreads();
    int base = lds[t] - tot;          // exclusive over buckets
    bbase[t] = base;
    if (t == 255) bbase[256] = NE;
    int run = base;
    for (int blk = 0; blk < B1; ++blk){
      roff[t * B1 + blk] = run;
      run += gcnt[t * B1 + blk];
    }
  }
}

// ---------------- FUSED: scan_apply (blocks 0..SCB-1) + bscatter (blocks SCB..) -
// Disjoint inputs (counts/boff vs ei/roff), both ready after scan_mid2 ->
// co-schedule instead of serial 4+8us.
__global__ __launch_bounds__(256) void k_ab(const int* __restrict__ counts, const int* __restrict__ boff,
                                            int* __restrict__ row_ptr,
                                            const void* __restrict__ ei, const int* __restrict__ flags,
                                            const int* __restrict__ roff, int2* __restrict__ ebuf){
  int t = threadIdx.x;
  if (blockIdx.x < SCB){                // ---- scan_apply part ----
    __shared__ int lds[256];
    int idx = blockIdx.x * 256 + t;
    int v = (idx < NN) ? counts[idx] : 0;
    lds[t] = v;
    for (int off = 1; off < 256; off <<= 1){
      __syncthreads();
      int u = (t >= off) ? lds[t - off] : 0;
      __syncthreads();
      lds[t] += u;
    }
    __syncthreads();
    if (idx < NN) row_ptr[idx] = boff[blockIdx.x] + lds[t] - v;
    return;
  }
  // ---- bscatter part ----
  __shared__ int lcur[256];
  int blk = blockIdx.x - SCB;
  lcur[t] = roff[t * B1 + blk];
  __syncthreads();
  int i0 = blk * CH, i1 = min(i0 + CH, NE);
  int i64m = flags[1];
  for (int i = i0 + t; i < i1; i += 256){
    int s, d;
    if (i64m){ s = (int)((const long long*)ei)[i]; d = (int)((const long long*)ei)[(size_t)NE + i]; }
    else     { s = ((const int*)ei)[i];            d = ((const int*)ei)[NE + i]; }
    int pos = atomicAdd(&lcur[d >> 8], 1);
    ebuf[pos] = make_int2(s, d);
  }
}

// ---------------- FUSED: refine (blocks 0..NB-1) + GEMM1 (blocks NB..) ---------
// Round-12 PMC proved co-residency works (scatter hidden under gemm window,
// window gemm-bound at 46us). refine (bucket-local, L2-resident, ~12us exposed
// in r12) now rides inside the same window. Independent: refine reads
// ebuf/bbase/row_ptr/cursor -> eidx; gemm reads w1t/x -> h1/al1.
constexpr int G1R = 128;                // rows per gemm block (2 x 64-row halves)
__global__ __launch_bounds__(256, 2) void k_rg1(const int2* __restrict__ ebuf, const int* __restrict__ bbase,
                                               const int* __restrict__ row_ptr, int* __restrict__ cursor,
                                               int* __restrict__ eidx,
                                               const void* __restrict__ xin,
                                               const int* __restrict__ flags,
                                               const bf16* __restrict__ w1t,
                                               const bf16* __restrict__ as1, const bf16* __restrict__ ad1,
                                               unsigned char* __restrict__ h1q,
                                               float* __restrict__ al_s1, float* __restrict__ al_d1){
  if (blockIdx.x < NB){                 // ---- refine part ----
    int b = blockIdx.x;
    int p0 = bbase[b], p1 = bbase[b + 1];
    for (int p = p0 + threadIdx.x; p < p1; p += 256){
      int2 e = ebuf[p];
      int pos = row_ptr[e.y] + atomicAdd(&cursor[e.y], 1);
      eidx[pos] = e.x;
    }
    return;
  }
  // ---- gemm1 part ----
  __shared__ __align__(16) short Ab[G1R * 64];   // 16 KB
  __shared__ __align__(16) short Bb[256 * 64];   // 32 KB
  int tid  = threadIdx.x;
  int w    = tid >> 6, lane = tid & 63, quad = lane >> 4, c = lane & 15;
  int row0 = (blockIdx.x - NB) * G1R;
  int f32m = flags[0];

  v4f acc[2][4][4];
  #pragma unroll
  for (int mh = 0; mh < 2; ++mh)
    #pragma unroll
    for (int mt = 0; mt < 4; ++mt)
      #pragma unroll
      for (int nt = 0; nt < 4; ++nt) acc[mh][mt][nt] = (v4f){0.f,0.f,0.f,0.f};

  // A staging: per half, 4 threads per row, 16 elems (2 chunks) each
  int arow = tid >> 2, aseg = tid & 3;
  int asw  = arow & 7;
  int grow0 = row0 + arow;      if (grow0 >= NN) grow0 = NN - 1;
  int grow1 = row0 + 64 + arow; if (grow1 >= NN) grow1 = NN - 1;
  // B staging: thread tid owns w1t row tid (64-elem k-slice = 8 chunks)
  int bsw  = tid & 7;

  float4 afl[2][4];  // f32 prefetch regs (per half)
  v8s    abf[2][2];  // bf16 prefetch regs (per half)
  v8s    breg[8];    // B prefetch regs

  auto loadA = [&](int ph){
    if (f32m){
      const float* s0 = (const float*)xin + (size_t)grow0 * CIN + ph*64 + aseg*16;
      const float* s1 = (const float*)xin + (size_t)grow1 * CIN + ph*64 + aseg*16;
      #pragma unroll
      for (int i = 0; i < 4; ++i){ afl[0][i] = *reinterpret_cast<const float4*>(s0 + i*4);
                                   afl[1][i] = *reinterpret_cast<const float4*>(s1 + i*4); }
    } else {
      const short* s0 = (const short*)xin + (size_t)grow0 * CIN + ph*64 + aseg*16;
      const short* s1 = (const short*)xin + (size_t)grow1 * CIN + ph*64 + aseg*16;
      abf[0][0] = *reinterpret_cast<const v8s*>(s0);
      abf[0][1] = *reinterpret_cast<const v8s*>(s0 + 8);
      abf[1][0] = *reinterpret_cast<const v8s*>(s1);
      abf[1][1] = *reinterpret_cast<const v8s*>(s1 + 8);
    }
  };
  auto loadB = [&](int ph){
    const short* src = (const short*)w1t + (size_t)tid * CIN + ph*64;
    #pragma unroll
    for (int j = 0; j < 8; ++j) breg[j] = *reinterpret_cast<const v8s*>(src + j*8);
  };
  auto stageA = [&](){
    #pragma unroll
    for (int mh = 0; mh < 2; ++mh){
      short* dst = &Ab[(mh*64 + arow) * 64];
      if (f32m){
        #pragma unroll
        for (int k = 0; k < 2; ++k){
          v8s t;
          t[0] = (short)f2bits(afl[mh][2*k].x);   t[1] = (short)f2bits(afl[mh][2*k].y);
          t[2] = (short)f2bits(afl[mh][2*k].z);   t[3] = (short)f2bits(afl[mh][2*k].w);
          t[4] = (short)f2bits(afl[mh][2*k+1].x); t[5] = (short)f2bits(afl[mh][2*k+1].y);
          t[6] = (short)f2bits(afl[mh][2*k+1].z); t[7] = (short)f2bits(afl[mh][2*k+1].w);
          *reinterpret_cast<v8s*>(dst + (((aseg*2 + k) ^ asw) << 3)) = t;
        }
      } else {
        #pragma unroll
        for (int k = 0; k < 2; ++k)
          *reinterpret_cast<v8s*>(dst + (((aseg*2 + k) ^ asw) << 3)) = abf[mh][k];
      }
    }
  };
  auto stageB = [&](){
    short* dst = &Bb[tid * 64];
    #pragma unroll
    for (int j = 0; j < 8; ++j)
      *reinterpret_cast<v8s*>(dst + ((j ^ bsw) << 3)) = breg[j];
  };

  loadA(0); loadB(0);
  #pragma unroll
  for (int ph = 0; ph < 4; ++ph){
    if (ph) __syncthreads();          // readers of previous phase done
    stageA(); stageB();
    __syncthreads();                  // data ready
    if (ph < 3){ loadA(ph + 1); loadB(ph + 1); }   // prefetch; lands under MFMA
    #pragma unroll
    for (int s = 0; s < 2; ++s){
      int ch = s*4 + quad;
      int sl = (ch ^ (c & 7)) << 3;
      v8s bfb[4];
      #pragma unroll
      for (int nt = 0; nt < 4; ++nt)
        bfb[nt] = *reinterpret_cast<const v8s*>(&Bb[(w*64 + nt*16 + c) * 64 + sl]);
      #pragma unroll
      for (int mh = 0; mh < 2; ++mh){
        v8s af[4];
        #pragma unroll
        for (int mt = 0; mt < 4; ++mt)
          af[mt] = *reinterpret_cast<const v8s*>(&Ab[(mh*64 + mt*16 + c) * 64 + sl]);
        #pragma unroll
        for (int mt = 0; mt < 4; ++mt)
          #pragma unroll
          for (int nt = 0; nt < 4; ++nt)
            acc[mh][mt][nt] = __builtin_amdgcn_mfma_f32_16x16x32_bf16(af[mt], bfb[nt], acc[mh][mt][nt], 0, 0, 0);
      }
    }
  }

  float as1v[4], ad1v[4];
  #pragma unroll
  for (int nt = 0; nt < 4; ++nt){
    as1v[nt] = b2f(as1[w*64 + nt*16 + c]);
    ad1v[nt] = b2f(ad1[w*64 + nt*16 + c]);
  }
  #pragma unroll
  for (int mh = 0; mh < 2; ++mh){
    int rowb = row0 + mh*64;
    #pragma unroll
    for (int mt = 0; mt < 4; ++mt){
      #pragma unroll
      for (int r = 0; r < 4; ++r){
        float ps = 0.f, pd = 0.f;
        #pragma unroll
        for (int nt = 0; nt < 4; ++nt){ ps += acc[mh][mt][nt][r] * as1v[nt]; pd += acc[mh][mt][nt][r] * ad1v[nt]; }
        #pragma unroll
        for (int off = 1; off < 16; off <<= 1){ ps += __shfl_xor(ps, off, 64); pd += __shfl_xor(pd, off, 64); }
        int row = rowb + mt*16 + quad*4 + r;
        if (c == 0 && row < NN){
          al_s1[row * NH + w] = ps;
          al_d1[row * NH + w] = pd;
        }
      }
    }
    #pragma unroll
    for (int mt = 0; mt < 4; ++mt){
      #pragma unroll
      for (int nt = 0; nt < 4; ++nt){
        #pragma unroll
        for (int r = 0; r < 4; r += 2){
          int row = rowb + mt*16 + quad*4 + r;
          if (row + 1 < NN){
            int pk = __builtin_amdgcn_cvt_pk_fp8_f32(acc[mh][mt][nt][r], acc[mh][mt][nt][r+1], 0, false);
            size_t col = w*64 + nt*16 + c;
            h1q[(size_t)row       * HC + col] = (unsigned char)(pk & 0xFF);
            h1q[(size_t)(row + 1) * HC + col] = (unsigned char)((pk >> 8) & 0xFF);
          } else if (row < NN){
            int pk = __builtin_amdgcn_cvt_pk_fp8_f32(acc[mh][mt][nt][r], acc[mh][mt][nt][r], 0, false);
            h1q[(size_t)row * HC + w*64 + nt*16 + c] = (unsigned char)(pk & 0xFF);
          }
        }
      }
    }
  }
}

// packed fp8->f32 accumulate: 2 channels per v_cvt_pk_f32_fp8.
#define ACCPK(W, U) { \
  v2f _lo = __builtin_amdgcn_cvt_pk_f32_fp8((int)(U), false); \
  v2f _hi = __builtin_amdgcn_cvt_pk_f32_fp8((int)(U), true);  \
  a0 += (W) * _lo.x; a1 += (W) * _lo.y;                       \
  a2 += (W) * _hi.x; a3 += (W) * _hi.y; }

// ---------------- gather layer 1 (round-3 structure + packed fp8 cvt) ----------
__global__ __launch_bounds__(256) void k_gather1(const int* __restrict__ row_ptr, const int* __restrict__ eidx,
                                                 const float* __restrict__ al_s1, const float* __restrict__ al_d1,
                                                 const unsigned* __restrict__ h1v, const bf16* __restrict__ b1,
                                                 bf16* __restrict__ y1){
  int lane = threadIdx.x & 63;
  int n = blockIdx.x * 4 + (threadIdx.x >> 6);
  int h = lane >> 4;
  int p0 = __builtin_amdgcn_readfirstlane(row_ptr[n]);
  int p1 = __builtin_amdgcn_readfirstlane(row_ptr[n + 1]);
  float ad_h = al_d1[n * NH + h];
  // self-loop contribution (src == dst == n)
  float wss = __expf(lrelu(al_s1[n * NH + h] + ad_h));
  unsigned us = h1v[(size_t)n * 64 + lane];
  float den = wss;
  float a0 = 0.f, a1 = 0.f, a2 = 0.f, a3 = 0.f;
  ACCPK(wss, us)
  int p = p0;
  for (; p + 3 < p1; p += 4){
    int sA = __builtin_amdgcn_readfirstlane(eidx[p]);
    int sB = __builtin_amdgcn_readfirstlane(eidx[p + 1]);
    int sC = __builtin_amdgcn_readfirstlane(eidx[p + 2]);
    int sD = __builtin_amdgcn_readfirstlane(eidx[p + 3]);
    float wA = __expf(lrelu(al_s1[sA * NH + h] + ad_h));
    float wB = __expf(lrelu(al_s1[sB * NH + h] + ad_h));
    float wC = __expf(lrelu(al_s1[sC * NH + h] + ad_h));
    float wD = __expf(lrelu(al_s1[sD * NH + h] + ad_h));
    unsigned uA = h1v[(size_t)sA * 64 + lane];
    unsigned uB = h1v[(size_t)sB * 64 + lane];
    unsigned uC = h1v[(size_t)sC * 64 + lane];
    unsigned uD = h1v[(size_t)sD * 64 + lane];
    den += (wA + wB) + (wC + wD);
    ACCPK(wA, uA)
    ACCPK(wB, uB)
    ACCPK(wC, uC)
    ACCPK(wD, uD)
  }
  for (; p < p1; ++p){
    int s = __builtin_amdgcn_readfirstlane(eidx[p]);
    float w = __expf(lrelu(al_s1[s * NH + h] + ad_h));
    unsigned u = h1v[(size_t)s * 64 + lane];
    den += w;
    ACCPK(w, u)
  }
  float inv = 1.f / (den + 1e-16f);
  ushort4 bb = reinterpret_cast<const ushort4*>(b1)[lane];
  ushort4 o;
  o.x = f2bits(fmaxf(a0 * inv + bits2f(bb.x), 0.f));
  o.y = f2bits(fmaxf(a1 * inv + bits2f(bb.y), 0.f));
  o.z = f2bits(fmaxf(a2 * inv + bits2f(bb.z), 0.f));
  o.w = f2bits(fmaxf(a3 * inv + bits2f(bb.w), 0.f));
  reinterpret_cast<ushort4*>(y1)[(size_t)n * 64 + lane] = o;
}

// ---------------- GEMM2 (MFMA, W2T in LDS) + fused al2 + fp8 h2 (64B rows) -----
constexpr int W2LP = 260;
__global__ __launch_bounds__(256) void k_gemm2(const bf16* __restrict__ y1, const bf16* __restrict__ w2t,
                                               const bf16* __restrict__ as2, const bf16* __restrict__ ad2,
                                               unsigned char* __restrict__ h2q, float* __restrict__ al_s2,
                                               float* __restrict__ al_d2){
  __shared__ short Wb[NPAD * W2LP];
  int tid = threadIdx.x;
  int w = tid >> 6, lane = tid & 63, quad = lane >> 4, c = lane & 15;
  int m0 = blockIdx.x * 64 + w * 16;
  for (int idx = tid; idx < NPAD * 32; idx += 256){
    int n = idx >> 5, sg = idx & 31;
    *reinterpret_cast<v8s*>(&Wb[n * W2LP + sg * 8]) =
      *reinterpret_cast<const v8s*>((const short*)w2t + (size_t)n * CIN + sg * 8);
  }
  int arow = m0 + c; if (arow >= NN) arow = NN - 1;
  const short* ar = (const short*)y1 + (size_t)arow * HC + quad * 8;
  v8s a[8];
  #pragma unroll
  for (int i = 0; i < 8; ++i) a[i] = *reinterpret_cast<const v8s*>(ar + i * 32);
  __syncthreads();

  v4f acc[3];
  #pragma unroll
  for (int t = 0; t < 3; ++t) acc[t] = (v4f){0.f, 0.f, 0.f, 0.f};
  #pragma unroll
  for (int k = 0; k < 8; ++k){
    int ch = k*4 + quad;
    #pragma unroll
    for (int t = 0; t < 3; ++t){
      v8s b = *reinterpret_cast<const v8s*>(&Wb[(t*16 + c) * W2LP + ch * 8]);
      acc[t] = __builtin_amdgcn_mfma_f32_16x16x32_bf16(a[k], b, acc[t], 0, 0, 0);
    }
  }
  float as2f[3], ad2f[3];
  #pragma unroll
  for (int t = 0; t < 3; ++t){
    int col = t*16 + c;
    as2f[t] = (col < NOUT) ? b2f(as2[col]) : 0.f;
    ad2f[t] = (col < NOUT) ? b2f(ad2[col]) : 0.f;
  }
  #pragma unroll
  for (int r = 0; r < 4; ++r){
    int row = m0 + quad*4 + r;
    float ps = 0.f, pd = 0.f;
    #pragma unroll
    for (int t = 0; t < 3; ++t){ ps += acc[t][r] * as2f[t]; pd += acc[t][r] * ad2f[t]; }
    #pragma unroll
    for (int off = 1; off < 16; off <<= 1){ ps += __shfl_xor(ps, off, 64); pd += __shfl_xor(pd, off, 64); }
    if (row < NN && c == 0){ al_s2[row] = ps; al_d2[row] = pd; }
  }
  // fp8 h2 store (64B rows; alphas above computed from fp32 accs)
  #pragma unroll
  for (int t = 0; t < 3; ++t){
    int col = t*16 + c;
    if (col < NOUT){
      #pragma unroll
      for (int r = 0; r < 4; r += 2){
        int row = m0 + quad*4 + r;
        int pk = __builtin_amdgcn_cvt_pk_fp8_f32(acc[t][r], acc[t][r+1], 0, false);
        if (row < NN)     h2q[(size_t)row       * 64 + col] = (unsigned char)(pk & 0xFF);
        if (row + 1 < NN) h2q[(size_t)(row + 1) * 64 + col] = (unsigned char)((pk >> 8) & 0xFF);
      }
    }
  }
}

// ---------------- gather layer 2: fused ew, quad-parallel, 4-deep unroll -------
__global__ __launch_bounds__(256) void k_gather2(const int* __restrict__ row_ptr, const int* __restrict__ eidx,
                                                 const float* __restrict__ al_s2, const float* __restrict__ al_d2,
                                                 const unsigned char* __restrict__ h2q, const bf16* __restrict__ b2v,
                                                 const int* __restrict__ flags, void* __restrict__ out){
  int lane = threadIdx.x & 63;
  int n = blockIdx.x * 4 + (threadIdx.x >> 6);
  int q = lane >> 4, c = lane & 15;
  bool act = (c < 10);                      // 10 dwords cover the 40 cols
  int p0 = __builtin_amdgcn_readfirstlane(row_ptr[n]);
  int p1 = __builtin_amdgcn_readfirstlane(row_ptr[n + 1]);
  const unsigned* h2v = reinterpret_cast<const unsigned*>(h2q);
  float adn = al_d2[n];                     // wave-uniform
  float den = 0.f, a0 = 0.f, a1 = 0.f, a2 = 0.f, a3 = 0.f;
  if (q == 0){                              // analytic self-loop, counted once
    float wss = __expf(lrelu(al_s2[n] + adn));
    den = wss;
    if (act){
      unsigned u = h2v[(size_t)n * 16 + c];
      ACCPK(wss, u)
    }
  }
  int p = p0 + q;
  for (; p + 12 < p1; p += 16){             // 4 edges per slot in flight
    int sA = eidx[p], sB = eidx[p + 4], sC = eidx[p + 8], sD = eidx[p + 12];
    float wA = __expf(lrelu(al_s2[sA] + adn));
    float wB = __expf(lrelu(al_s2[sB] + adn));
    float wC = __expf(lrelu(al_s2[sC] + adn));
    float wD = __expf(lrelu(al_s2[sD] + adn));
    unsigned uA = act ? h2v[(size_t)sA * 16 + c] : 0u;
    unsigned uB = act ? h2v[(size_t)sB * 16 + c] : 0u;
    unsigned uC = act ? h2v[(size_t)sC * 16 + c] : 0u;
    unsigned uD = act ? h2v[(size_t)sD * 16 + c] : 0u;
    den += (wA + wB) + (wC + wD);
    ACCPK(wA, uA)
    ACCPK(wB, uB)
    ACCPK(wC, uC)
    ACCPK(wD, uD)
  }
  for (; p + 4 < p1; p += 8){
    int sA = eidx[p], sB = eidx[p + 4];
    float wA = __expf(lrelu(al_s2[sA] + adn));
    float wB = __expf(lrelu(al_s2[sB] + adn));
    unsigned uA = act ? h2v[(size_t)sA * 16 + c] : 0u;
    unsigned uB = act ? h2v[(size_t)sB * 16 + c] : 0u;
    den += wA + wB;
    ACCPK(wA, uA)
    ACCPK(wB, uB)
  }
  if (p < p1){
    int s = eidx[p];
    float w = __expf(lrelu(al_s2[s] + adn));
    unsigned u = act ? h2v[(size_t)s * 16 + c] : 0u;
    den += w;
    ACCPK(w, u)
  }
  // reduce across the 4 quads (lanes within a quad hold identical den)
  #pragma unroll
  for (int off = 16; off <= 32; off <<= 1){
    den += __shfl_xor(den, off, 64);
    a0  += __shfl_xor(a0,  off, 64);
    a1  += __shfl_xor(a1,  off, 64);
    a2  += __shfl_xor(a2,  off, 64);
    a3  += __shfl_xor(a3,  off, 64);
  }
  float inv = 1.f / (den + 1e-16f);
  float v0 = -INFINITY, v1 = -INFINITY, v2 = -INFINITY, v3 = -INFINITY;
  if (act){
    ushort4 bb = *reinterpret_cast<const ushort4*>(reinterpret_cast<const unsigned short*>(b2v) + 4 * c);
    v0 = a0 * inv + bits2f(bb.x);
    v1 = a1 * inv + bits2f(bb.y);
    v2 = a2 * inv + bits2f(bb.z);
    v3 = a3 * inv + bits2f(bb.w);
  }
  float M = wave_max(fmaxf(fmaxf(v0, v1), fmaxf(v2, v3)));
  float ex = (q == 0 && act)
           ? (__expf(v0 - M) + __expf(v1 - M)) + (__expf(v2 - M) + __expf(v3 - M)) : 0.f;
  float S = wave_sum(ex);
  if (q == 0 && act){
    float lg = M + __logf(S);
    if (flags[0]){
      float4 o = {v0 - lg, v1 - lg, v2 - lg, v3 - lg};
      *reinterpret_cast<float4*>((float*)out + (size_t)n * NOUT + 4 * c) = o;
    } else {
      ushort4 o;
      o.x = f2bits(v0 - lg); o.y = f2bits(v1 - lg);
      o.z = f2bits(v2 - lg); o.w = f2bits(v3 - lg);
      *reinterpret_cast<ushort4*>((unsigned short*)out + (size_t)n * NOUT + 4 * c) = o;
    }
  }
}

extern "C" void kernel_launch(void* const* d_in, const int* in_sizes, int n_in,
                              void* d_out, int out_size, void* d_ws, size_t ws_size,
                              hipStream_t stream) {
  const void* x   = d_in[0];
  const void* ei  = d_in[1];
  const void* W1  = d_in[2];
  const void* as1 = d_in[3];
  const void* ad1 = d_in[4];
  const void* b1  = d_in[5];
  const void* W2  = d_in[6];
  const void* as2 = d_in[7];
  const void* ad2 = d_in[8];
  const void* b2  = d_in[9];

  char* ws = (char*)d_ws;
  int*   flags   = (int*)  (ws + WS_FLAGS);
  bf16*  w1t     = (bf16*) (ws + WS_W1T);
  bf16*  as1n    = (bf16*) (ws + WS_AS1N);
  bf16*  ad1n    = (bf16*) (ws + WS_AD1N);
  bf16*  b1n     = (bf16*) (ws + WS_B1N);
  bf16*  w2t     = (bf16*) (ws + WS_W2T);
  bf16*  as2n    = (bf16*) (ws + WS_AS2N);
  bf16*  ad2n    = (bf16*) (ws + WS_AD2N);
  bf16*  b2n     = (bf16*) (ws + WS_B2N);
  int*   counts  = (int*)  (ws + WS_COUNTS);
  int*   cursor  = (int*)  (ws + WS_CURSOR);
  int*   row_ptr = (int*)  (ws + WS_ROWPTR);
  int*   eidx    = (int*)  (ws + WS_EIDX);
  unsigned char* h1q = (unsigned char*)(ws + WS_H1);
  float* al_s1   = (float*)(ws + WS_ALS1);
  float* al_d1   = (float*)(ws + WS_ALD1);
  bf16*  y1      = (bf16*) (ws + WS_Y1);
  unsigned char* h2q = (unsigned char*)(ws + WS_H2);
  float* al_s2   = (float*)(ws + WS_ALS2);
  float* al_d2   = (float*)(ws + WS_ALD2);
  int*   bsum    = (int*)  (ws + WS_BSUM);
  int*   boff    = (int*)  (ws + WS_BOFF);
  int*   gcnt    = (int*)  (ws + WS_GCNT);
  int*   roff    = (int*)  (ws + WS_ROFF);
  int*   bbase   = (int*)  (ws + WS_BBASE);
  int2*  ebuf    = (int2*) (ws + WS_EBUF);

  k_init    <<<INIT_B + 1, 256, 0, stream>>>((const unsigned short*)x, (const unsigned*)ei, ws);
  k_convert <<<1024, 256, 0, stream>>>(W1, as1, ad1, b1, W2, as2, ad2, b2, ei, ws);

  k_scan_part <<<SCB, 256, 0, stream>>>(counts, bsum);
  k_scan_mid2 <<<2, 256, 0, stream>>>(bsum, boff, row_ptr, gcnt, roff, bbase);
  k_ab        <<<SCB + B1, 256, 0, stream>>>(counts, boff, row_ptr, ei, flags, roff, ebuf);

  k_rg1    <<<NB + (NN + G1R - 1) / G1R, 256, 0, stream>>>(ebuf, bbase, row_ptr, cursor, eidx,
                                                           x, flags, w1t, as1n, ad1n, h1q, al_s1, al_d1);
  k_gather1<<<NN / 4, 256, 0, stream>>>(row_ptr, eidx, al_s1, al_d1, (const unsigned*)h1q, b1n, y1);
  k_gemm2  <<<(NN + 63) / 64, 256, 0, stream>>>(y1, w2t, as2n, ad2n, h2q, al_s2, al_d2);
  k_gather2<<<NN / 4, 256, 0, stream>>>(row_ptr, eidx, al_s2, al_d2, h2q, b2n, flags, d_out);
}

// Round 14
// 276.605 us; speedup vs baseline: 1.0368x; 1.0368x over previous
//
#include <hip/hip_runtime.h>
#include <hip/hip_bf16.h>

typedef __hip_bfloat16 bf16;
typedef short v8s __attribute__((ext_vector_type(8)));   // 8 bf16 (4 VGPRs), MFMA A/B frag
typedef float v4f __attribute__((ext_vector_type(4)));   // MFMA C/D frag
typedef float v2f __attribute__((ext_vector_type(2)));   // cvt_pk_f32_fp8 result

constexpr int NN    = 50000;   // nodes
constexpr int NE    = 800000;  // raw edges (self-loops handled analytically)
constexpr int CIN   = 256;
constexpr int HC    = 256;     // H*C
constexpr int NH    = 4;
constexpr int NOUT  = 40;
constexpr int NPAD  = 48;      // W2T padded cols (3 x 16)
constexpr int SCB   = 196;     // scan blocks (196*256 >= NN)
constexpr int B1    = 128;     // edge-pass blocks
constexpr int CH    = (NE + B1 - 1) / B1;   // 6250 edges/chunk

// ---------------- workspace layout ----------------
constexpr size_t al256(size_t x){ return (x + 255) & ~(size_t)255; }
constexpr size_t WS_FLAGS = 0;                                   // 2 ints
constexpr size_t WS_EW1   = 256;                                 // NE float4 (unused; layout kept)
constexpr size_t WS_W1T   = al256(WS_EW1   + (size_t)NE*16);     // [n][k] 256x256 bf16
constexpr size_t WS_AS1N  = al256(WS_W1T   + (size_t)CIN*HC*2);
constexpr size_t WS_AD1N  = al256(WS_AS1N  + HC*2);
constexpr size_t WS_B1N   = al256(WS_AD1N  + HC*2);
constexpr size_t WS_W2T   = al256(WS_B1N   + HC*2);              // [n][k] 48x256 bf16 (zero-padded)
constexpr size_t WS_AS2N  = al256(WS_W2T   + (size_t)NPAD*HC*2);
constexpr size_t WS_AD2N  = al256(WS_AS2N  + NOUT*2);
constexpr size_t WS_B2N   = al256(WS_AD2N  + NOUT*2);
constexpr size_t WS_COUNTS= al256(WS_B2N   + NOUT*2);
constexpr size_t WS_CURSOR= al256(WS_COUNTS+ (size_t)NN*4);
constexpr size_t WS_ROWPTR= al256(WS_CURSOR+ (size_t)NN*4);
constexpr size_t WS_EIDX  = al256(WS_ROWPTR+ (size_t)(NN+1)*4);  // NE int (src per CSR slot)
constexpr size_t WS_H1    = al256(WS_EIDX  + (size_t)NE*4);      // NN*HC fp8 (1B)
constexpr size_t WS_ALS1  = al256(WS_H1    + (size_t)NN*HC);
constexpr size_t WS_ALD1  = al256(WS_ALS1  + (size_t)NN*NH*4);
constexpr size_t WS_Y1    = al256(WS_ALD1  + (size_t)NN*NH*4);   // NN*HC bf16
constexpr size_t WS_H2    = al256(WS_Y1    + (size_t)NN*HC*2);   // NN*64 fp8 (64B row = 1 line)
constexpr size_t WS_ALS2  = al256(WS_H2    + (size_t)NN*64);
constexpr size_t WS_ALD2  = al256(WS_ALS2  + (size_t)NN*4);
constexpr size_t WS_EW2   = al256(WS_ALD2  + (size_t)NN*4);      // NE float (unused; layout kept)
constexpr size_t WS_BSUM  = al256(WS_EW2   + (size_t)NE*4);      // 256 int
constexpr size_t WS_BOFF  = al256(WS_BSUM  + 1024);              // 256 int

// ---------------- convert virtual index space (weights only) ----------------
constexpr int CV_W1  = 0;
constexpr int CV_AS1 = CV_W1  + CIN*HC;
constexpr int CV_AD1 = CV_AS1 + HC;
constexpr int CV_B1  = CV_AD1 + HC;
constexpr int CV_W2  = CV_B1  + HC;
constexpr int CV_AS2 = CV_W2  + HC*NOUT;
constexpr int CV_AD2 = CV_AS2 + NOUT;
constexpr int CV_B2  = CV_AD2 + NOUT;
constexpr int CV_END = CV_B2  + NOUT;

__device__ __forceinline__ float b2f(bf16 v) { return __bfloat162float(v); }
__device__ __forceinline__ bf16  f2b(float v){ return __float2bfloat16(v); }
__device__ __forceinline__ float bits2f(unsigned short u){ return __uint_as_float(((unsigned)u) << 16); }
__device__ __forceinline__ unsigned short f2bits(float v){
  bf16 t = __float2bfloat16(v);
  return *reinterpret_cast<unsigned short*>(&t);
}
__device__ __forceinline__ float lrelu(float x){ return x > 0.f ? x : 0.2f * x; }

__device__ __forceinline__ float wave_sum(float v){
  #pragma unroll
  for (int off = 32; off; off >>= 1) v += __shfl_xor(v, off, 64);
  return v;
}
__device__ __forceinline__ float wave_max(float v){
  #pragma unroll
  for (int off = 32; off; off >>= 1) v = fmaxf(v, __shfl_xor(v, off, 64));
  return v;
}

// ---------------- init: zero counts/cursor/w2t-pad + dtype detection ----------
constexpr int INIT_B = (2*NN + 2048 + 255) / 256;   // zero-fill blocks
__global__ __launch_bounds__(256) void k_init(const unsigned short* __restrict__ xu,
                                              const unsigned* __restrict__ eu,
                                              char* __restrict__ ws){
  int b = blockIdx.x;
  if (b == INIT_B){                       // detect block (wave 0 only)
    int lane = threadIdx.x;
    if (lane < 64){
      int* flags = (int*)(ws + WS_FLAGS);
      int cnt = 0;
      for (int i = lane; i < 256; i += 64){
        int e = (xu[i] >> 7) & 0xFF;
        cnt += (e >= 0x60 && e <= 0x8F) ? 1 : 0;
      }
      #pragma unroll
      for (int off = 32; off; off >>= 1) cnt += __shfl_xor(cnt, off, 64);
      unsigned odd = eu[2 * lane + 1];
      #pragma unroll
      for (int off = 32; off; off >>= 1) odd |= __shfl_xor(odd, off, 64);
      if (lane == 0){
        flags[0] = (cnt < 218) ? 1 : 0;   // 1 = floats are f32
        flags[1] = (odd == 0)  ? 1 : 0;   // 1 = edges are int64
      }
    }
    return;
  }
  int g = b * 256 + threadIdx.x;
  int* counts = (int*)(ws + WS_COUNTS);
  int* cursor = (int*)(ws + WS_CURSOR);
  bf16* w2t   = (bf16*)(ws + WS_W2T);
  if (g < NN) counts[g] = 0;
  else if (g < 2*NN) cursor[g - NN] = 0;
  else if (g < 2*NN + 2048){
    int i = g - 2*NN;                     // zero pad rows 40..47 of w2t
    w2t[(NOUT + (i >> 8)) * CIN + (i & 255)] = f2b(0.f);
  }
}

__device__ __forceinline__ bf16 cvt_b(const void* src, int i, int f32m){
  if (f32m) return __float2bfloat16(((const float*)src)[i]);
  return ((const bf16*)src)[i];
}

// convert weights + fused dst histogram (counts only; r11-best config — no
// bucket machinery; r12/r13 ledger showed gcnt+exposed edge pass cost more
// than the in-window scatter it saves).
__global__ __launch_bounds__(256) void k_convert(
    const void* __restrict__ W1,
    const void* __restrict__ as1,const void* __restrict__ ad1,
    const void* __restrict__ b1, const void* __restrict__ W2,
    const void* __restrict__ as2,const void* __restrict__ ad2,
    const void* __restrict__ b2, const void* __restrict__ ei,
    char* __restrict__ ws){
  const int* flags = (const int*)(ws + WS_FLAGS);
  int f32m = flags[0], i64m = flags[1];
  int blk = blockIdx.x, tid = threadIdx.x;
  if (blk < B1){
    int* counts = (int*)(ws + WS_COUNTS);
    int i0 = blk * CH, i1 = min(i0 + CH, NE);
    for (int i = i0 + tid; i < i1; i += 256){
      int d = i64m ? (int)((const long long*)ei)[(size_t)NE + i] : ((const int*)ei)[NE + i];
      atomicAdd(&counts[d], 1);
    }
    return;
  }
  bf16* w1t  = (bf16*)(ws + WS_W1T);
  bf16* as1n = (bf16*)(ws + WS_AS1N);
  bf16* ad1n = (bf16*)(ws + WS_AD1N);
  bf16* b1n  = (bf16*)(ws + WS_B1N);
  bf16* w2t  = (bf16*)(ws + WS_W2T);
  bf16* as2n = (bf16*)(ws + WS_AS2N);
  bf16* ad2n = (bf16*)(ws + WS_AD2N);
  bf16* b2n  = (bf16*)(ws + WS_B2N);
  for (int g = (blk - B1) * 256 + tid; g < CV_END; g += (gridDim.x - B1) * 256){
    if      (g < CV_AS1){ int i = g-CV_W1; int k = i >> 8, n = i & 255;
      w1t[n*CIN + k] = cvt_b(W1, i, f32m); }                       // transpose
    else if (g < CV_AD1) as1n[g-CV_AS1] = cvt_b(as1,g-CV_AS1, f32m);
    else if (g < CV_B1 ) ad1n[g-CV_AD1] = cvt_b(ad1,g-CV_AD1, f32m);
    else if (g < CV_W2 ) b1n [g-CV_B1 ] = cvt_b(b1, g-CV_B1,  f32m);
    else if (g < CV_AS2){ int i = g-CV_W2; int k = i / NOUT, n = i - k*NOUT;
      w2t[n*CIN + k] = cvt_b(W2, i, f32m); }                       // transpose (rows 40..47 pre-zeroed)
    else if (g < CV_AD2) as2n[g-CV_AS2] = cvt_b(as2,g-CV_AS2, f32m);
    else if (g < CV_B2 ) ad2n[g-CV_AD2] = cvt_b(ad2,g-CV_AD2, f32m);
    else                 b2n [g-CV_B2 ] = cvt_b(b2, g-CV_B2,  f32m);
  }
}

// ---------------- parallel CSR scan (real edges only; self-loops analytic) -----
__global__ __launch_bounds__(256) void k_scan_part(const int* __restrict__ counts, int* __restrict__ bsum){
  __shared__ int lds[256];
  int t = threadIdx.x;
  int idx = blockIdx.x * 256 + t;
  int v = (idx < NN) ? counts[idx] : 0;
  lds[t] = v;
  #pragma unroll
  for (int s = 128; s > 0; s >>= 1){
    __syncthreads();
    if (t < s) lds[t] += lds[t + s];
  }
  if (t == 0) bsum[blockIdx.x] = lds[0];
}

__global__ __launch_bounds__(256) void k_scan_mid(const int* __restrict__ bsum, int* __restrict__ boff,
                                                  int* __restrict__ row_ptr){
  __shared__ int lds[256];
  int t = threadIdx.x;
  int v = (t < SCB) ? bsum[t] : 0;
  lds[t] = v;
  for (int off = 1; off < 256; off <<= 1){
    __syncthreads();
    int u = (t >= off) ? lds[t - off] : 0;
    __syncthreads();
    lds[t] += u;
  }
  __syncthreads();
  if (t < SCB) boff[t] = lds[t] - v;   // exclusive
  if (t == 0) row_ptr[NN] = NE;
}

__global__ __launch_bounds__(256) void k_scan_apply(const int* __restrict__ counts, const int* __restrict__ boff,
                                                    int* __restrict__ row_ptr){
  __shared__ int lds[256];
  int t = threadIdx.x;
  int idx = blockIdx.x * 256 + t;
  int v = (idx < NN) ? counts[idx] : 0;
  lds[t] = v;
  for (int off = 1; off < 256; off <<= 1){
    __syncthreads();
    int u = (t >= off) ? lds[t - off] : 0;
    __syncthreads();
    lds[t] += u;
  }
  __syncthreads();
  if (idx < NN) row_ptr[idx] = boff[blockIdx.x] + lds[t] - v;
}

// ---------------- FUSED: CSR scatter (blocks 0..B1-1) + GEMM1 (blocks B1..) ----
// Round-11 best (281.5us total). Scatter is latency-bound random-atomic traffic;
// gemm1 is LDS/MFMA-bound; mutually independent + resource-complementary, so
// co-scheduling on one grid converts serial 90us into one ~71us window that
// also absorbs the harness-fill contention tax. r12/r13 probed both bucketed
// alternatives — both worse end-to-end.
constexpr int G1R = 128;                // rows per gemm block (2 x 64-row halves)
__global__ __launch_bounds__(256, 2) void k_sg1(const void* __restrict__ ei,
                                               const int* __restrict__ row_ptr, int* __restrict__ cursor,
                                               int* __restrict__ eidx,
                                               const void* __restrict__ xin,
                                               const int* __restrict__ flags,
                                               const bf16* __restrict__ w1t,
                                               const bf16* __restrict__ as1, const bf16* __restrict__ ad1,
                                               unsigned char* __restrict__ h1q,
                                               float* __restrict__ al_s1, float* __restrict__ al_d1){
  if (blockIdx.x < B1){                 // ---- scatter part ----
    int tid = threadIdx.x, blk = blockIdx.x;
    int i0 = blk * CH, i1 = min(i0 + CH, NE);
    int i64m = flags[1];
    for (int i = i0 + tid; i < i1; i += 256){
      int s, d;
      if (i64m){ s = (int)((const long long*)ei)[i]; d = (int)((const long long*)ei)[(size_t)NE + i]; }
      else     { s = ((const int*)ei)[i];            d = ((const int*)ei)[NE + i]; }
      int pos = row_ptr[d] + atomicAdd(&cursor[d], 1);
      eidx[pos] = s;
    }
    return;
  }
  // ---- gemm1 part ----
  __shared__ __align__(16) short Ab[G1R * 64];   // 16 KB
  __shared__ __align__(16) short Bb[256 * 64];   // 32 KB
  int tid  = threadIdx.x;
  int w    = tid >> 6, lane = tid & 63, quad = lane >> 4, c = lane & 15;
  int row0 = (blockIdx.x - B1) * G1R;
  int f32m = flags[0];

  v4f acc[2][4][4];
  #pragma unroll
  for (int mh = 0; mh < 2; ++mh)
    #pragma unroll
    for (int mt = 0; mt < 4; ++mt)
      #pragma unroll
      for (int nt = 0; nt < 4; ++nt) acc[mh][mt][nt] = (v4f){0.f,0.f,0.f,0.f};

  // A staging: per half, 4 threads per row, 16 elems (2 chunks) each
  int arow = tid >> 2, aseg = tid & 3;
  int asw  = arow & 7;
  int grow0 = row0 + arow;      if (grow0 >= NN) grow0 = NN - 1;
  int grow1 = row0 + 64 + arow; if (grow1 >= NN) grow1 = NN - 1;
  // B staging: thread tid owns w1t row tid (64-elem k-slice = 8 chunks)
  int bsw  = tid & 7;

  float4 afl[2][4];  // f32 prefetch regs (per half)
  v8s    abf[2][2];  // bf16 prefetch regs (per half)
  v8s    breg[8];    // B prefetch regs

  auto loadA = [&](int ph){
    if (f32m){
      const float* s0 = (const float*)xin + (size_t)grow0 * CIN + ph*64 + aseg*16;
      const float* s1 = (const float*)xin + (size_t)grow1 * CIN + ph*64 + aseg*16;
      #pragma unroll
      for (int i = 0; i < 4; ++i){ afl[0][i] = *reinterpret_cast<const float4*>(s0 + i*4);
                                   afl[1][i] = *reinterpret_cast<const float4*>(s1 + i*4); }
    } else {
      const short* s0 = (const short*)xin + (size_t)grow0 * CIN + ph*64 + aseg*16;
      const short* s1 = (const short*)xin + (size_t)grow1 * CIN + ph*64 + aseg*16;
      abf[0][0] = *reinterpret_cast<const v8s*>(s0);
      abf[0][1] = *reinterpret_cast<const v8s*>(s0 + 8);
      abf[1][0] = *reinterpret_cast<const v8s*>(s1);
      abf[1][1] = *reinterpret_cast<const v8s*>(s1 + 8);
    }
  };
  auto loadB = [&](int ph){
    const short* src = (const short*)w1t + (size_t)tid * CIN + ph*64;
    #pragma unroll
    for (int j = 0; j < 8; ++j) breg[j] = *reinterpret_cast<const v8s*>(src + j*8);
  };
  auto stageA = [&](){
    #pragma unroll
    for (int mh = 0; mh < 2; ++mh){
      short* dst = &Ab[(mh*64 + arow) * 64];
      if (f32m){
        #pragma unroll
        for (int k = 0; k < 2; ++k){
          v8s t;
          t[0] = (short)f2bits(afl[mh][2*k].x);   t[1] = (short)f2bits(afl[mh][2*k].y);
          t[2] = (short)f2bits(afl[mh][2*k].z);   t[3] = (short)f2bits(afl[mh][2*k].w);
          t[4] = (short)f2bits(afl[mh][2*k+1].x); t[5] = (short)f2bits(afl[mh][2*k+1].y);
          t[6] = (short)f2bits(afl[mh][2*k+1].z); t[7] = (short)f2bits(afl[mh][2*k+1].w);
          *reinterpret_cast<v8s*>(dst + (((aseg*2 + k) ^ asw) << 3)) = t;
        }
      } else {
        #pragma unroll
        for (int k = 0; k < 2; ++k)
          *reinterpret_cast<v8s*>(dst + (((aseg*2 + k) ^ asw) << 3)) = abf[mh][k];
      }
    }
  };
  auto stageB = [&](){
    short* dst = &Bb[tid * 64];
    #pragma unroll
    for (int j = 0; j < 8; ++j)
      *reinterpret_cast<v8s*>(dst + ((j ^ bsw) << 3)) = breg[j];
  };

  loadA(0); loadB(0);
  #pragma unroll
  for (int ph = 0; ph < 4; ++ph){
    if (ph) __syncthreads();          // readers of previous phase done
    stageA(); stageB();
    __syncthreads();                  // data ready
    if (ph < 3){ loadA(ph + 1); loadB(ph + 1); }   // prefetch; lands under MFMA
    #pragma unroll
    for (int s = 0; s < 2; ++s){
      int ch = s*4 + quad;
      int sl = (ch ^ (c & 7)) << 3;
      v8s bfb[4];
      #pragma unroll
      for (int nt = 0; nt < 4; ++nt)
        bfb[nt] = *reinterpret_cast<const v8s*>(&Bb[(w*64 + nt*16 + c) * 64 + sl]);
      #pragma unroll
      for (int mh = 0; mh < 2; ++mh){
        v8s af[4];
        #pragma unroll
        for (int mt = 0; mt < 4; ++mt)
          af[mt] = *reinterpret_cast<const v8s*>(&Ab[(mh*64 + mt*16 + c) * 64 + sl]);
        #pragma unroll
        for (int mt = 0; mt < 4; ++mt)
          #pragma unroll
          for (int nt = 0; nt < 4; ++nt)
            acc[mh][mt][nt] = __builtin_amdgcn_mfma_f32_16x16x32_bf16(af[mt], bfb[nt], acc[mh][mt][nt], 0, 0, 0);
      }
    }
  }

  float as1v[4], ad1v[4];
  #pragma unroll
  for (int nt = 0; nt < 4; ++nt){
    as1v[nt] = b2f(as1[w*64 + nt*16 + c]);
    ad1v[nt] = b2f(ad1[w*64 + nt*16 + c]);
  }
  #pragma unroll
  for (int mh = 0; mh < 2; ++mh){
    int rowb = row0 + mh*64;
    #pragma unroll
    for (int mt = 0; mt < 4; ++mt){
      #pragma unroll
      for (int r = 0; r < 4; ++r){
        float ps = 0.f, pd = 0.f;
        #pragma unroll
        for (int nt = 0; nt < 4; ++nt){ ps += acc[mh][mt][nt][r] * as1v[nt]; pd += acc[mh][mt][nt][r] * ad1v[nt]; }
        #pragma unroll
        for (int off = 1; off < 16; off <<= 1){ ps += __shfl_xor(ps, off, 64); pd += __shfl_xor(pd, off, 64); }
        int row = rowb + mt*16 + quad*4 + r;
        if (c == 0 && row < NN){
          al_s1[row * NH + w] = ps;
          al_d1[row * NH + w] = pd;
        }
      }
    }
    #pragma unroll
    for (int mt = 0; mt < 4; ++mt){
      #pragma unroll
      for (int nt = 0; nt < 4; ++nt){
        #pragma unroll
        for (int r = 0; r < 4; r += 2){
          int row = rowb + mt*16 + quad*4 + r;
          if (row + 1 < NN){
            int pk = __builtin_amdgcn_cvt_pk_fp8_f32(acc[mh][mt][nt][r], acc[mh][mt][nt][r+1], 0, false);
            size_t col = w*64 + nt*16 + c;
            h1q[(size_t)row       * HC + col] = (unsigned char)(pk & 0xFF);
            h1q[(size_t)(row + 1) * HC + col] = (unsigned char)((pk >> 8) & 0xFF);
          } else if (row < NN){
            int pk = __builtin_amdgcn_cvt_pk_fp8_f32(acc[mh][mt][nt][r], acc[mh][mt][nt][r], 0, false);
            h1q[(size_t)row * HC + w*64 + nt*16 + c] = (unsigned char)(pk & 0xFF);
          }
        }
      }
    }
  }
}

// packed fp8->f32 accumulate: 2 channels per v_cvt_pk_f32_fp8.
#define ACCPK(W, U) { \
  v2f _lo = __builtin_amdgcn_cvt_pk_f32_fp8((int)(U), false); \
  v2f _hi = __builtin_amdgcn_cvt_pk_f32_fp8((int)(U), true);  \
  a0 += (W) * _lo.x; a1 += (W) * _lo.y;                       \
  a2 += (W) * _hi.x; a3 += (W) * _hi.y; }

// ---------------- gather layer 1 (round-3 structure + packed fp8 cvt) ----------
__global__ __launch_bounds__(256) void k_gather1(const int* __restrict__ row_ptr, const int* __restrict__ eidx,
                                                 const float* __restrict__ al_s1, const float* __restrict__ al_d1,
                                                 const unsigned* __restrict__ h1v, const bf16* __restrict__ b1,
                                                 bf16* __restrict__ y1){
  int lane = threadIdx.x & 63;
  int n = blockIdx.x * 4 + (threadIdx.x >> 6);
  int h = lane >> 4;
  int p0 = __builtin_amdgcn_readfirstlane(row_ptr[n]);
  int p1 = __builtin_amdgcn_readfirstlane(row_ptr[n + 1]);
  float ad_h = al_d1[n * NH + h];
  // self-loop contribution (src == dst == n)
  float wss = __expf(lrelu(al_s1[n * NH + h] + ad_h));
  unsigned us = h1v[(size_t)n * 64 + lane];
  float den = wss;
  float a0 = 0.f, a1 = 0.f, a2 = 0.f, a3 = 0.f;
  ACCPK(wss, us)
  int p = p0;
  for (; p + 3 < p1; p += 4){
    int sA = __builtin_amdgcn_readfirstlane(eidx[p]);
    int sB = __builtin_amdgcn_readfirstlane(eidx[p + 1]);
    int sC = __builtin_amdgcn_readfirstlane(eidx[p + 2]);
    int sD = __builtin_amdgcn_readfirstlane(eidx[p + 3]);
    float wA = __expf(lrelu(al_s1[sA * NH + h] + ad_h));
    float wB = __expf(lrelu(al_s1[sB * NH + h] + ad_h));
    float wC = __expf(lrelu(al_s1[sC * NH + h] + ad_h));
    float wD = __expf(lrelu(al_s1[sD * NH + h] + ad_h));
    unsigned uA = h1v[(size_t)sA * 64 + lane];
    unsigned uB = h1v[(size_t)sB * 64 + lane];
    unsigned uC = h1v[(size_t)sC * 64 + lane];
    unsigned uD = h1v[(size_t)sD * 64 + lane];
    den += (wA + wB) + (wC + wD);
    ACCPK(wA, uA)
    ACCPK(wB, uB)
    ACCPK(wC, uC)
    ACCPK(wD, uD)
  }
  for (; p < p1; ++p){
    int s = __builtin_amdgcn_readfirstlane(eidx[p]);
    float w = __expf(lrelu(al_s1[s * NH + h] + ad_h));
    unsigned u = h1v[(size_t)s * 64 + lane];
    den += w;
    ACCPK(w, u)
  }
  float inv = 1.f / (den + 1e-16f);
  ushort4 bb = reinterpret_cast<const ushort4*>(b1)[lane];
  ushort4 o;
  o.x = f2bits(fmaxf(a0 * inv + bits2f(bb.x), 0.f));
  o.y = f2bits(fmaxf(a1 * inv + bits2f(bb.y), 0.f));
  o.z = f2bits(fmaxf(a2 * inv + bits2f(bb.z), 0.f));
  o.w = f2bits(fmaxf(a3 * inv + bits2f(bb.w), 0.f));
  reinterpret_cast<ushort4*>(y1)[(size_t)n * 64 + lane] = o;
}

// ---------------- GEMM2 (MFMA, W2T in LDS) + fused al2 + fp8 h2 (64B rows) -----
constexpr int W2LP = 260;
__global__ __launch_bounds__(256) void k_gemm2(const bf16* __restrict__ y1, const bf16* __restrict__ w2t,
                                               const bf16* __restrict__ as2, const bf16* __restrict__ ad2,
                                               unsigned char* __restrict__ h2q, float* __restrict__ al_s2,
                                               float* __restrict__ al_d2){
  __shared__ short Wb[NPAD * W2LP];
  int tid = threadIdx.x;
  int w = tid >> 6, lane = tid & 63, quad = lane >> 4, c = lane & 15;
  int m0 = blockIdx.x * 64 + w * 16;
  for (int idx = tid; idx < NPAD * 32; idx += 256){
    int n = idx >> 5, sg = idx & 31;
    *reinterpret_cast<v8s*>(&Wb[n * W2LP + sg * 8]) =
      *reinterpret_cast<const v8s*>((const short*)w2t + (size_t)n * CIN + sg * 8);
  }
  int arow = m0 + c; if (arow >= NN) arow = NN - 1;
  const short* ar = (const short*)y1 + (size_t)arow * HC + quad * 8;
  v8s a[8];
  #pragma unroll
  for (int i = 0; i < 8; ++i) a[i] = *reinterpret_cast<const v8s*>(ar + i * 32);
  __syncthreads();

  v4f acc[3];
  #pragma unroll
  for (int t = 0; t < 3; ++t) acc[t] = (v4f){0.f, 0.f, 0.f, 0.f};
  #pragma unroll
  for (int k = 0; k < 8; ++k){
    int ch = k*4 + quad;
    #pragma unroll
    for (int t = 0; t < 3; ++t){
      v8s b = *reinterpret_cast<const v8s*>(&Wb[(t*16 + c) * W2LP + ch * 8]);
      acc[t] = __builtin_amdgcn_mfma_f32_16x16x32_bf16(a[k], b, acc[t], 0, 0, 0);
    }
  }
  float as2f[3], ad2f[3];
  #pragma unroll
  for (int t = 0; t < 3; ++t){
    int col = t*16 + c;
    as2f[t] = (col < NOUT) ? b2f(as2[col]) : 0.f;
    ad2f[t] = (col < NOUT) ? b2f(ad2[col]) : 0.f;
  }
  #pragma unroll
  for (int r = 0; r < 4; ++r){
    int row = m0 + quad*4 + r;
    float ps = 0.f, pd = 0.f;
    #pragma unroll
    for (int t = 0; t < 3; ++t){ ps += acc[t][r] * as2f[t]; pd += acc[t][r] * ad2f[t]; }
    #pragma unroll
    for (int off = 1; off < 16; off <<= 1){ ps += __shfl_xor(ps, off, 64); pd += __shfl_xor(pd, off, 64); }
    if (row < NN && c == 0){ al_s2[row] = ps; al_d2[row] = pd; }
  }
  // fp8 h2 store (64B rows; alphas above computed from fp32 accs)
  #pragma unroll
  for (int t = 0; t < 3; ++t){
    int col = t*16 + c;
    if (col < NOUT){
      #pragma unroll
      for (int r = 0; r < 4; r += 2){
        int row = m0 + quad*4 + r;
        int pk = __builtin_amdgcn_cvt_pk_fp8_f32(acc[t][r], acc[t][r+1], 0, false);
        if (row < NN)     h2q[(size_t)row       * 64 + col] = (unsigned char)(pk & 0xFF);
        if (row + 1 < NN) h2q[(size_t)(row + 1) * 64 + col] = (unsigned char)((pk >> 8) & 0xFF);
      }
    }
  }
}

// ---------------- gather layer 2: fused ew, quad-parallel, 4-deep unroll -------
__global__ __launch_bounds__(256) void k_gather2(const int* __restrict__ row_ptr, const int* __restrict__ eidx,
                                                 const float* __restrict__ al_s2, const float* __restrict__ al_d2,
                                                 const unsigned char* __restrict__ h2q, const bf16* __restrict__ b2v,
                                                 const int* __restrict__ flags, void* __restrict__ out){
  int lane = threadIdx.x & 63;
  int n = blockIdx.x * 4 + (threadIdx.x >> 6);
  int q = lane >> 4, c = lane & 15;
  bool act = (c < 10);                      // 10 dwords cover the 40 cols
  int p0 = __builtin_amdgcn_readfirstlane(row_ptr[n]);
  int p1 = __builtin_amdgcn_readfirstlane(row_ptr[n + 1]);
  const unsigned* h2v = reinterpret_cast<const unsigned*>(h2q);
  float adn = al_d2[n];                     // wave-uniform
  float den = 0.f, a0 = 0.f, a1 = 0.f, a2 = 0.f, a3 = 0.f;
  if (q == 0){                              // analytic self-loop, counted once
    float wss = __expf(lrelu(al_s2[n] + adn));
    den = wss;
    if (act){
      unsigned u = h2v[(size_t)n * 16 + c];
      ACCPK(wss, u)
    }
  }
  int p = p0 + q;
  for (; p + 12 < p1; p += 16){             // 4 edges per slot in flight
    int sA = eidx[p], sB = eidx[p + 4], sC = eidx[p + 8], sD = eidx[p + 12];
    float wA = __expf(lrelu(al_s2[sA] + adn));
    float wB = __expf(lrelu(al_s2[sB] + adn));
    float wC = __expf(lrelu(al_s2[sC] + adn));
    float wD = __expf(lrelu(al_s2[sD] + adn));
    unsigned uA = act ? h2v[(size_t)sA * 16 + c] : 0u;
    unsigned uB = act ? h2v[(size_t)sB * 16 + c] : 0u;
    unsigned uC = act ? h2v[(size_t)sC * 16 + c] : 0u;
    unsigned uD = act ? h2v[(size_t)sD * 16 + c] : 0u;
    den += (wA + wB) + (wC + wD);
    ACCPK(wA, uA)
    ACCPK(wB, uB)
    ACCPK(wC, uC)
    ACCPK(wD, uD)
  }
  for (; p + 4 < p1; p += 8){
    int sA = eidx[p], sB = eidx[p + 4];
    float wA = __expf(lrelu(al_s2[sA] + adn));
    float wB = __expf(lrelu(al_s2[sB] + adn));
    unsigned uA = act ? h2v[(size_t)sA * 16 + c] : 0u;
    unsigned uB = act ? h2v[(size_t)sB * 16 + c] : 0u;
    den += wA + wB;
    ACCPK(wA, uA)
    ACCPK(wB, uB)
  }
  if (p < p1){
    int s = eidx[p];
    float w = __expf(lrelu(al_s2[s] + adn));
    unsigned u = act ? h2v[(size_t)s * 16 + c] : 0u;
    den += w;
    ACCPK(w, u)
  }
  // reduce across the 4 quads (lanes within a quad hold identical den)
  #pragma unroll
  for (int off = 16; off <= 32; off <<= 1){
    den += __shfl_xor(den, off, 64);
    a0  += __shfl_xor(a0,  off, 64);
    a1  += __shfl_xor(a1,  off, 64);
    a2  += __shfl_xor(a2,  off, 64);
    a3  += __shfl_xor(a3,  off, 64);
  }
  float inv = 1.f / (den + 1e-16f);
  float v0 = -INFINITY, v1 = -INFINITY, v2 = -INFINITY, v3 = -INFINITY;
  if (act){
    ushort4 bb = *reinterpret_cast<const ushort4*>(reinterpret_cast<const unsigned short*>(b2v) + 4 * c);
    v0 = a0 * inv + bits2f(bb.x);
    v1 = a1 * inv + bits2f(bb.y);
    v2 = a2 * inv + bits2f(bb.z);
    v3 = a3 * inv + bits2f(bb.w);
  }
  float M = wave_max(fmaxf(fmaxf(v0, v1), fmaxf(v2, v3)));
  float ex = (q == 0 && act)
           ? (__expf(v0 - M) + __expf(v1 - M)) + (__expf(v2 - M) + __expf(v3 - M)) : 0.f;
  float S = wave_sum(ex);
  if (q == 0 && act){
    float lg = M + __logf(S);
    if (flags[0]){
      float4 o = {v0 - lg, v1 - lg, v2 - lg, v3 - lg};
      *reinterpret_cast<float4*>((float*)out + (size_t)n * NOUT + 4 * c) = o;
    } else {
      ushort4 o;
      o.x = f2bits(v0 - lg); o.y = f2bits(v1 - lg);
      o.z = f2bits(v2 - lg); o.w = f2bits(v3 - lg);
      *reinterpret_cast<ushort4*>((unsigned short*)out + (size_t)n * NOUT + 4 * c) = o;
    }
  }
}

extern "C" void kernel_launch(void* const* d_in, const int* in_sizes, int n_in,
                              void* d_out, int out_size, void* d_ws, size_t ws_size,
                              hipStream_t stream) {
  const void* x   = d_in[0];
  const void* ei  = d_in[1];
  const void* W1  = d_in[2];
  const void* as1 = d_in[3];
  const void* ad1 = d_in[4];
  const void* b1  = d_in[5];
  const void* W2  = d_in[6];
  const void* as2 = d_in[7];
  const void* ad2 = d_in[8];
  const void* b2  = d_in[9];

  char* ws = (char*)d_ws;
  int*   flags   = (int*)  (ws + WS_FLAGS);
  bf16*  w1t     = (bf16*) (ws + WS_W1T);
  bf16*  as1n    = (bf16*) (ws + WS_AS1N);
  bf16*  ad1n    = (bf16*) (ws + WS_AD1N);
  bf16*  b1n     = (bf16*) (ws + WS_B1N);
  bf16*  w2t     = (bf16*) (ws + WS_W2T);
  bf16*  as2n    = (bf16*) (ws + WS_AS2N);
  bf16*  ad2n    = (bf16*) (ws + WS_AD2N);
  bf16*  b2n     = (bf16*) (ws + WS_B2N);
  int*   counts  = (int*)  (ws + WS_COUNTS);
  int*   cursor  = (int*)  (ws + WS_CURSOR);
  int*   row_ptr = (int*)  (ws + WS_ROWPTR);
  int*   eidx    = (int*)  (ws + WS_EIDX);
  unsigned char* h1q = (unsigned char*)(ws + WS_H1);
  float* al_s1   = (float*)(ws + WS_ALS1);
  float* al_d1   = (float*)(ws + WS_ALD1);
  bf16*  y1      = (bf16*) (ws + WS_Y1);
  unsigned char* h2q = (unsigned char*)(ws + WS_H2);
  float* al_s2   = (float*)(ws + WS_ALS2);
  float* al_d2   = (float*)(ws + WS_ALD2);
  int*   bsum    = (int*)  (ws + WS_BSUM);
  int*   boff    = (int*)  (ws + WS_BOFF);

  k_init    <<<INIT_B + 1, 256, 0, stream>>>((const unsigned short*)x, (const unsigned*)ei, ws);
  k_convert <<<1024, 256, 0, stream>>>(W1, as1, ad1, b1, W2, as2, ad2, b2, ei, ws);

  k_scan_part <<<SCB, 256, 0, stream>>>(counts, bsum);
  k_scan_mid  <<<1, 256, 0, stream>>>(bsum, boff, row_ptr);
  k_scan_apply<<<SCB, 256, 0, stream>>>(counts, boff, row_ptr);

  k_sg1    <<<B1 + (NN + G1R - 1) / G1R, 256, 0, stream>>>(ei, row_ptr, cursor, eidx,
                                                           x, flags, w1t, as1n, ad1n, h1q, al_s1, al_d1);
  k_gather1<<<NN / 4, 256, 0, stream>>>(row_ptr, eidx, al_s1, al_d1, (const unsigned*)h1q, b1n, y1);
  k_gemm2  <<<(NN + 63) / 64, 256, 0, stream>>>(y1, w2t, as2n, ad2n, h2q, al_s2, al_d2);
  k_gather2<<<NN / 4, 256, 0, stream>>>(row_ptr, eidx, al_s2, al_d2, h2q, b2n, flags, d_out);
}